// Round 18
// baseline (115.925 us; speedup 1.0000x reference)
//
#include <hip/hip_runtime.h>
#include <hip/hip_fp16.h>
#include <math.h>

// Normalization_60095182406123
//
// Separable 4D Gaussian filter of x^2 over axes (freq, orient, y, x):
//   out[c,y,x] = sum g3[df] g3[do] g32[dy] g32[dx] * xsq[c+(df-1)*16+(do-1)*2, y+dy-16, x+dx-16]
// c = img*192 + freq*16 + orient*2 + phase (same flat layout in and out).
//
// Pass 1 (unchanged since R8): x^2 + orient(3) + freq(3) + blur_x(32) -> ws (fp16), ~40 us
// Pass 2 (R18): R15's 143-row/64KB tile + async split-stage pipeline (T14):
//   - all stage loads issued as named uint4 regs up-front (no load->write chains)
//   - chunk0 (rows 0..86) written, then RAW barrier (s_waitcnt lgkmcnt(0) +
//     s_barrier + sched_barrier) — NOT __syncthreads, which drains vmcnt(0)
//     and would kill the in-flight chunk1 loads
//   - subtile A (outputs 0..55) computes while chunk1 loads fly
//   - chunk1 (rows 87..142, disjoint from A's reads) written, barrier,
//     subtile B (outputs 56..111)
//   Occupancy was proven NOT the lever (R15 16 waves == R17 32 waves == ~70us);
//   the barrier-drain serialization is the target.
//
// ws needs 768*224*224*2 = 77,070,336 bytes of d_ws.

#define SZW   224
#define PLANE (224*224)
#define PW    256          // floats per LDS row in pass1: 16 zero | 224 | 15 zero | 1

struct GaussArgs {
    float wx[32];   // 32-tap Gaussian (l=32, w=1), matches reference _gauss
    float w30;      // 3-tap edge   = c*exp(-0.5)
    float w31;      // 3-tap center = c
};

// within-row float4-group swizzle (involution, preserves 8-group blocks)
__device__ __forceinline__ int swz(int g) { return g ^ ((g >> 3) & 7); }

__global__ __launch_bounds__(512, 6) void pass1_kernel(const float* __restrict__ in,
                                                       __half* __restrict__ ws,
                                                       const GaussArgs ga)
{
    __shared__ float s2[48 * PW];   // 49,152 B

    const int tid   = threadIdx.x;
    const int y     = blockIdx.x;          // 0..223
    const int by    = blockIdx.y;          // 0..5
    const int phase = by & 1;
    const int fg    = by >> 1;             // freq group: output f in [4fg, 4fg+4)
    const int img   = blockIdx.z;          // 0..3

    const float w31 = ga.w31;
    const float w30 = ga.w30;

    // ---- step 1: load x^2 (x-padded), orient 3-tap conv in regs, to LDS ----
    if (tid < 384) {
        const int lf  = tid >> 6;          // 0..5
        const int xp4 = tid & 63;
        const int f   = 4*fg - 1 + lf;     // -1..12
        const int gsw = swz(xp4);
        float4 a[8];
        if (f >= 0 && f < 12 && xp4 >= 4 && xp4 < 60) {
            const int x0 = xp4*4 - 16;     // 0..220, 16B-aligned
            const float* base = in + (size_t)(img*192 + f*16 + phase)*PLANE + y*SZW + x0;
            #pragma unroll
            for (int o = 0; o < 8; ++o) {
                float4 v = *reinterpret_cast<const float4*>(base + o*2*PLANE);
                a[o] = make_float4(v.x*v.x, v.y*v.y, v.z*v.z, v.w*v.w);
            }
        } else {
            #pragma unroll
            for (int o = 0; o < 8; ++o) a[o] = make_float4(0.f,0.f,0.f,0.f);
        }
        #pragma unroll
        for (int o = 0; o < 8; ++o) {
            float4 l = (o > 0) ? a[o-1] : make_float4(0.f,0.f,0.f,0.f);
            float4 r = (o < 7) ? a[o+1] : make_float4(0.f,0.f,0.f,0.f);
            float4 b;
            b.x = fmaf(w31, a[o].x, w30*(l.x + r.x));
            b.y = fmaf(w31, a[o].y, w30*(l.y + r.y));
            b.z = fmaf(w31, a[o].z, w30*(l.z + r.z));
            b.w = fmaf(w31, a[o].w, w30*(l.w + r.w));
            *reinterpret_cast<float4*>(&s2[(lf*8 + o)*PW + gsw*4]) = b;
        }
    }
    __syncthreads();

    // ---- step 2: freq 3-tap conv in place ----
    {
        const int o   = tid >> 6;          // 0..7
        const int xp4 = tid & 63;
        const int gsw = swz(xp4);
        float4 a[6];
        #pragma unroll
        for (int lf = 0; lf < 6; ++lf)
            a[lf] = *reinterpret_cast<const float4*>(&s2[(lf*8 + o)*PW + gsw*4]);
        #pragma unroll
        for (int lf = 1; lf < 5; ++lf) {
            float4 b;
            b.x = fmaf(w31, a[lf].x, w30*(a[lf-1].x + a[lf+1].x));
            b.y = fmaf(w31, a[lf].y, w30*(a[lf-1].y + a[lf+1].y));
            b.z = fmaf(w31, a[lf].z, w30*(a[lf-1].z + a[lf+1].z));
            b.w = fmaf(w31, a[lf].w, w30*(a[lf-1].w + a[lf+1].w));
            *reinterpret_cast<float4*>(&s2[(lf*8 + o)*PW + gsw*4]) = b;
        }
    }
    __syncthreads();

    // ---- step 3: 32-tap blur along x, 16 outputs/thread, fp16 store ----
    if (tid < 448) {
        const int r  = tid / 14;           // 0..31
        const int xg = tid - r*14;         // 0..13
        const int lf = 1 + (r >> 3);
        const int o  = r & 7;
        const int fo16 = (4*fg + (r >> 3))*16 + o*2;
        const int x0 = xg * 16;            // output x base (0..208)
        const int rowb = (lf*8 + o)*PW;
        const int g0 = 4*xg;

        float acc[16];
        #pragma unroll
        for (int j = 0; j < 16; ++j) acc[j] = 0.f;

        #pragma unroll
        for (int t = 0; t < 12; ++t) {
            const float4 q = *reinterpret_cast<const float4*>(
                &s2[rowb + swz(g0 + t)*4]);
            #pragma unroll
            for (int e = 0; e < 4; ++e) {
                const int m = 4*t + e;     // window float index 0..47
                const float qv = (e==0)?q.x:(e==1)?q.y:(e==2)?q.z:q.w;
                const int jlo = (m - 31 > 0) ? (m - 31) : 0;
                const int jhi = (m < 15) ? m : 15;
                #pragma unroll
                for (int j = jlo; j <= jhi; ++j)
                    acc[j] = fmaf(ga.wx[m - j], qv, acc[j]);
            }
        }

        union { uint4 u4[2]; __half2 h2[8]; } pk;
        #pragma unroll
        for (int s = 0; s < 8; ++s)
            pk.h2[s] = __floats2half2_rn(acc[2*s], acc[2*s+1]);

        __half* op = ws + (size_t)(img*192 + phase)*PLANE + (size_t)y*SZW
                        + (size_t)fo16*PLANE + x0;
        *reinterpret_cast<uint4*>(op)     = pk.u4[0];
        *reinterpret_cast<uint4*>(op + 8) = pk.u4[1];
    }
}

// one 14-output chunk of the y-blur (reads stage rows [14cc, 14cc+44])
__device__ __forceinline__ void p2_chunk(const __half* __restrict__ tile,
                                         const GaussArgs& ga,
                                         float* __restrict__ oc,
                                         int yb, int cc, int x0)
{
    const int sbase = cc * 14;
    float a0[14], a1[14];
    #pragma unroll
    for (int j = 0; j < 14; ++j) { a0[j] = 0.f; a1[j] = 0.f; }
    #pragma unroll
    for (int i = 0; i < 45; ++i) {
        const __half2 h = *reinterpret_cast<const __half2*>(&tile[(sbase + i)*SZW + x0]);
        const float2 f = __half22float2(h);
        const int jlo = (i - 31 > 0) ? (i - 31) : 0;
        const int jhi = (i < 13) ? i : 13;
        #pragma unroll
        for (int j = jlo; j <= jhi; ++j) {
            a0[j] = fmaf(ga.wx[i - j], f.x, a0[j]);
            a1[j] = fmaf(ga.wx[i - j], f.y, a1[j]);
        }
    }
    #pragma unroll
    for (int j = 0; j < 14; ++j)
        *reinterpret_cast<float2*>(oc + (size_t)(yb + cc*14 + j) * SZW) =
            make_float2(a0[j], a1[j]);
}

// Pass 2: y-blur, 143-row/64KB tile, async split-stage (see header comment).
#define P2R 143
__global__ __launch_bounds__(512, 4) void pass2_kernel(const __half* __restrict__ ws,
                                                       float* __restrict__ out,
                                                       const GaussArgs ga)
{
    __shared__ __half tile[P2R * SZW];   // 64,064 B

    const int tid = threadIdx.x;
    const int ch  = blockIdx.x;   // 0..767
    const int yb  = blockIdx.y * 112;

    const __half* wp = ws + (size_t)ch * PLANE;
    const uint4 Z = make_uint4(0u, 0u, 0u, 0u);

    // ---- issue chunk0 loads (stage rows 0..86 = 2436 items, <=5/thread) ----
    uint4 v0=Z, v1=Z, v2=Z, v3=Z, v4=Z;
    {
        int t, r, g, yy;
        t = tid;        r = t/28; g = t - r*28; yy = yb - 16 + r;
        if (yy >= 0 && yy < SZW) v0 = *reinterpret_cast<const uint4*>(wp + (size_t)yy*SZW + g*8);
        t = tid + 512;  r = t/28; g = t - r*28; yy = yb - 16 + r;
        if (yy >= 0 && yy < SZW) v1 = *reinterpret_cast<const uint4*>(wp + (size_t)yy*SZW + g*8);
        t = tid + 1024; r = t/28; g = t - r*28; yy = yb - 16 + r;
        if (yy >= 0 && yy < SZW) v2 = *reinterpret_cast<const uint4*>(wp + (size_t)yy*SZW + g*8);
        t = tid + 1536; r = t/28; g = t - r*28; yy = yb - 16 + r;
        if (yy >= 0 && yy < SZW) v3 = *reinterpret_cast<const uint4*>(wp + (size_t)yy*SZW + g*8);
        t = tid + 2048;
        if (t < 2436) {
            r = t/28; g = t - r*28; yy = yb - 16 + r;
            if (yy >= 0 && yy < SZW) v4 = *reinterpret_cast<const uint4*>(wp + (size_t)yy*SZW + g*8);
        }
    }
    // ---- issue chunk1 loads (stage rows 87..142 = 1568 items, <=4/thread) ----
    uint4 u0=Z, u1=Z, u2=Z, u3=Z;
    {
        int t, r, g, yy;
        t = tid;        r = 87 + t/28; g = t - (t/28)*28; yy = yb - 16 + r;
        if (yy < SZW) u0 = *reinterpret_cast<const uint4*>(wp + (size_t)yy*SZW + g*8);
        t = tid + 512;  r = 87 + t/28; g = t - (t/28)*28; yy = yb - 16 + r;
        if (yy < SZW) u1 = *reinterpret_cast<const uint4*>(wp + (size_t)yy*SZW + g*8);
        t = tid + 1024; r = 87 + t/28; g = t - (t/28)*28; yy = yb - 16 + r;
        if (yy < SZW) u2 = *reinterpret_cast<const uint4*>(wp + (size_t)yy*SZW + g*8);
        t = tid + 1536;
        if (t < 1568) {
            r = 87 + t/28; g = t - (t/28)*28; yy = yb - 16 + r;
            if (yy < SZW) u3 = *reinterpret_cast<const uint4*>(wp + (size_t)yy*SZW + g*8);
        }
    }

    // ---- write chunk0 to LDS (byte-linear: item t -> byte 16t) ----
    {
        int t, r, g;
        t = tid;        r = t/28; g = t - r*28; *reinterpret_cast<uint4*>(&tile[r*SZW + g*8]) = v0;
        t = tid + 512;  r = t/28; g = t - r*28; *reinterpret_cast<uint4*>(&tile[r*SZW + g*8]) = v1;
        t = tid + 1024; r = t/28; g = t - r*28; *reinterpret_cast<uint4*>(&tile[r*SZW + g*8]) = v2;
        t = tid + 1536; r = t/28; g = t - r*28; *reinterpret_cast<uint4*>(&tile[r*SZW + g*8]) = v3;
        t = tid + 2048;
        if (t < 2436) { r = t/28; g = t - r*28; *reinterpret_cast<uint4*>(&tile[r*SZW + g*8]) = v4; }
    }
    // raw barrier: drain LDS writes only — chunk1 global loads stay in flight
    asm volatile("s_waitcnt lgkmcnt(0)" ::: "memory");
    __builtin_amdgcn_s_barrier();
    __builtin_amdgcn_sched_barrier(0);

    const int cp = tid % 112;
    const int gq = tid / 112;          // 0..3 for tid<448
    const int x0 = cp * 2;
    float* oc = out + (size_t)ch * PLANE + x0;

    // ---- subtile A: chunks 0..3 (reads rows 0..86; u-loads fly underneath) ----
    if (tid < 448)
        p2_chunk(tile, ga, oc, yb, gq, x0);

    // ---- write chunk1 to LDS (rows 87..142 — disjoint from A's reads) ----
    {
        int t, r, g;
        t = tid;        r = 87 + t/28; g = t - (t/28)*28; *reinterpret_cast<uint4*>(&tile[r*SZW + g*8]) = u0;
        t = tid + 512;  r = 87 + t/28; g = t - (t/28)*28; *reinterpret_cast<uint4*>(&tile[r*SZW + g*8]) = u1;
        t = tid + 1024; r = 87 + t/28; g = t - (t/28)*28; *reinterpret_cast<uint4*>(&tile[r*SZW + g*8]) = u2;
        t = tid + 1536;
        if (t < 1568) { r = 87 + t/28; g = t - (t/28)*28; *reinterpret_cast<uint4*>(&tile[r*SZW + g*8]) = u3; }
    }
    asm volatile("s_waitcnt lgkmcnt(0)" ::: "memory");
    __builtin_amdgcn_s_barrier();
    __builtin_amdgcn_sched_barrier(0);

    // ---- subtile B: chunks 4..7 (reads rows 56..142) ----
    if (tid < 448)
        p2_chunk(tile, ga, oc, yb, 4 + gq, x0);
}

extern "C" void kernel_launch(void* const* d_in, const int* in_sizes, int n_in,
                              void* d_out, int out_size, void* d_ws, size_t ws_size,
                              hipStream_t stream)
{
    const float* x  = (const float*)d_in[0];
    float*      out = (float*)d_out;
    __half*     ws  = (__half*)d_ws;  // 768*224*224*2 = 77,070,336 B

    // Host-computed Gaussian weights (double precision then rounded to f32 —
    // matches reference _gauss float64 path).
    GaussArgs ga;
    const double c0 = 1.0 / sqrt(2.0 * 3.14159265358979323846);
    for (int k = 0; k < 32; ++k) {
        double t = -1.0 + 2.0 * (double)k / 31.0;
        ga.wx[k] = (float)(c0 * exp(-t * t / 2.0));
    }
    ga.w31 = (float)c0;
    ga.w30 = (float)(c0 * exp(-0.5));

    dim3 g1(SZW, 6, 4);               // (y, phase*freqgroup, img)
    pass1_kernel<<<g1, 512, 0, stream>>>(x, ws, ga);
    dim3 g2(768, 2);                  // (channel, y-tile)
    pass2_kernel<<<g2, 512, 0, stream>>>(ws, out, ga);
}

// Round 19
// 105.093 us; speedup vs baseline: 1.1031x; 1.1031x over previous
//
#include <hip/hip_runtime.h>
#include <hip/hip_fp16.h>
#include <math.h>

// Normalization_60095182406123
//
// Separable 4D Gaussian filter of x^2 over axes (freq, orient, y, x):
//   out[c,y,x] = sum g3[df] g3[do] g32[dy] g32[dx] * xsq[c+(df-1)*16+(do-1)*2, y+dy-16, x+dx-16]
// c = img*192 + freq*16 + orient*2 + phase (same flat layout in and out).
//
// Pass 1: x^2 + orient(3) + freq(3) + blur_x(32) -> ws (fp16).  R19: PW=260
//   (row stride 1040 B) so step-3 waves spanning ~5 rows hit distinct bank
//   quads — targets the residual 9.9e6 inter-row conflicts (swz() fixed only
//   the intra-row term).
// Pass 2: blur_y(32) fp16->fp32, 143-row/64KB LDS tile (R15 geometry).  R19:
//   stage via __builtin_amdgcn_global_load_lds width=16 (no VGPR round-trip,
//   no ds_writes). Tile mapping is lane-linear (item t -> LDS byte 16t).
//   Full-exec with clamped source rows; boundary rows zeroed post-barrier.
//
// ws needs 768*224*224*2 = 77,070,336 bytes of d_ws.

#define SZW   224
#define PLANE (224*224)
#define PW    260          // floats per pass1 LDS row (was 256; +4 de-aliases rows)

struct GaussArgs {
    float wx[32];   // 32-tap Gaussian (l=32, w=1), matches reference _gauss
    float w30;      // 3-tap edge   = c*exp(-0.5)
    float w31;      // 3-tap center = c
};

// within-row float4-group swizzle (involution, preserves 8-group blocks)
__device__ __forceinline__ int swz(int g) { return g ^ ((g >> 3) & 7); }

__global__ __launch_bounds__(512, 6) void pass1_kernel(const float* __restrict__ in,
                                                       __half* __restrict__ ws,
                                                       const GaussArgs ga)
{
    __shared__ float s2[48 * PW];   // 49,920 B -> still 3 blocks/CU

    const int tid   = threadIdx.x;
    const int y     = blockIdx.x;          // 0..223
    const int by    = blockIdx.y;          // 0..5
    const int phase = by & 1;
    const int fg    = by >> 1;             // freq group: output f in [4fg, 4fg+4)
    const int img   = blockIdx.z;          // 0..3

    const float w31 = ga.w31;
    const float w30 = ga.w30;

    // ---- step 1: load x^2 (x-padded), orient 3-tap conv in regs, to LDS ----
    if (tid < 384) {
        const int lf  = tid >> 6;          // 0..5
        const int xp4 = tid & 63;
        const int f   = 4*fg - 1 + lf;     // -1..12
        const int gsw = swz(xp4);
        float4 a[8];
        if (f >= 0 && f < 12 && xp4 >= 4 && xp4 < 60) {
            const int x0 = xp4*4 - 16;     // 0..220, 16B-aligned
            const float* base = in + (size_t)(img*192 + f*16 + phase)*PLANE + y*SZW + x0;
            #pragma unroll
            for (int o = 0; o < 8; ++o) {
                float4 v = *reinterpret_cast<const float4*>(base + o*2*PLANE);
                a[o] = make_float4(v.x*v.x, v.y*v.y, v.z*v.z, v.w*v.w);
            }
        } else {
            #pragma unroll
            for (int o = 0; o < 8; ++o) a[o] = make_float4(0.f,0.f,0.f,0.f);
        }
        #pragma unroll
        for (int o = 0; o < 8; ++o) {
            float4 l = (o > 0) ? a[o-1] : make_float4(0.f,0.f,0.f,0.f);
            float4 r = (o < 7) ? a[o+1] : make_float4(0.f,0.f,0.f,0.f);
            float4 b;
            b.x = fmaf(w31, a[o].x, w30*(l.x + r.x));
            b.y = fmaf(w31, a[o].y, w30*(l.y + r.y));
            b.z = fmaf(w31, a[o].z, w30*(l.z + r.z));
            b.w = fmaf(w31, a[o].w, w30*(l.w + r.w));
            *reinterpret_cast<float4*>(&s2[(lf*8 + o)*PW + gsw*4]) = b;
        }
    }
    __syncthreads();

    // ---- step 2: freq 3-tap conv in place ----
    {
        const int o   = tid >> 6;          // 0..7
        const int xp4 = tid & 63;
        const int gsw = swz(xp4);
        float4 a[6];
        #pragma unroll
        for (int lf = 0; lf < 6; ++lf)
            a[lf] = *reinterpret_cast<const float4*>(&s2[(lf*8 + o)*PW + gsw*4]);
        #pragma unroll
        for (int lf = 1; lf < 5; ++lf) {
            float4 b;
            b.x = fmaf(w31, a[lf].x, w30*(a[lf-1].x + a[lf+1].x));
            b.y = fmaf(w31, a[lf].y, w30*(a[lf-1].y + a[lf+1].y));
            b.z = fmaf(w31, a[lf].z, w30*(a[lf-1].z + a[lf+1].z));
            b.w = fmaf(w31, a[lf].w, w30*(a[lf-1].w + a[lf+1].w));
            *reinterpret_cast<float4*>(&s2[(lf*8 + o)*PW + gsw*4]) = b;
        }
    }
    __syncthreads();

    // ---- step 3: 32-tap blur along x, 16 outputs/thread, fp16 store ----
    if (tid < 448) {
        const int r  = tid / 14;           // 0..31
        const int xg = tid - r*14;         // 0..13
        const int lf = 1 + (r >> 3);
        const int o  = r & 7;
        const int fo16 = (4*fg + (r >> 3))*16 + o*2;
        const int x0 = xg * 16;            // output x base (0..208)
        const int rowb = (lf*8 + o)*PW;
        const int g0 = 4*xg;

        float acc[16];
        #pragma unroll
        for (int j = 0; j < 16; ++j) acc[j] = 0.f;

        #pragma unroll
        for (int t = 0; t < 12; ++t) {
            const float4 q = *reinterpret_cast<const float4*>(
                &s2[rowb + swz(g0 + t)*4]);
            #pragma unroll
            for (int e = 0; e < 4; ++e) {
                const int m = 4*t + e;     // window float index 0..47
                const float qv = (e==0)?q.x:(e==1)?q.y:(e==2)?q.z:q.w;
                const int jlo = (m - 31 > 0) ? (m - 31) : 0;
                const int jhi = (m < 15) ? m : 15;
                #pragma unroll
                for (int j = jlo; j <= jhi; ++j)
                    acc[j] = fmaf(ga.wx[m - j], qv, acc[j]);
            }
        }

        union { uint4 u4[2]; __half2 h2[8]; } pk;
        #pragma unroll
        for (int s = 0; s < 8; ++s)
            pk.h2[s] = __floats2half2_rn(acc[2*s], acc[2*s+1]);

        __half* op = ws + (size_t)(img*192 + phase)*PLANE + (size_t)y*SZW
                        + (size_t)fo16*PLANE + x0;
        *reinterpret_cast<uint4*>(op)     = pk.u4[0];
        *reinterpret_cast<uint4*>(op + 8) = pk.u4[1];
    }
}

// one 14-output chunk of the y-blur (reads stage rows [14cc, 14cc+44])
__device__ __forceinline__ void p2_chunk(const __half* __restrict__ tile,
                                         const GaussArgs& ga,
                                         float* __restrict__ oc,
                                         int yb, int cc, int x0)
{
    const int sbase = cc * 14;
    float a0[14], a1[14];
    #pragma unroll
    for (int j = 0; j < 14; ++j) { a0[j] = 0.f; a1[j] = 0.f; }
    #pragma unroll
    for (int i = 0; i < 45; ++i) {
        const __half2 h = *reinterpret_cast<const __half2*>(&tile[(sbase + i)*SZW + x0]);
        const float2 f = __half22float2(h);
        const int jlo = (i - 31 > 0) ? (i - 31) : 0;
        const int jhi = (i < 13) ? i : 13;
        #pragma unroll
        for (int j = jlo; j <= jhi; ++j) {
            a0[j] = fmaf(ga.wx[i - j], f.x, a0[j]);
            a1[j] = fmaf(ga.wx[i - j], f.y, a1[j]);
        }
    }
    #pragma unroll
    for (int j = 0; j < 14; ++j)
        *reinterpret_cast<float2*>(oc + (size_t)(yb + cc*14 + j) * SZW) =
            make_float2(a0[j], a1[j]);
}

// Pass 2: y-blur, 143-row/64KB tile staged via global_load_lds (width 16).
// Item t (t = tid + k*512, lane-linear) -> LDS byte 16t = row t/28, group t%28.
#define P2R 143
__global__ __launch_bounds__(512, 4) void pass2_kernel(const __half* __restrict__ ws,
                                                       float* __restrict__ out,
                                                       const GaussArgs ga)
{
    __shared__ __half tile[P2R * SZW];   // 64,064 B

    const int tid = threadIdx.x;
    const int ch  = blockIdx.x;   // 0..767
    const int yb  = blockIdx.y * 112;

    const __half* wp = ws + (size_t)ch * PLANE;

    // ---- async stage: full-exec global_load_lds, source rows clamped ----
    for (int t = tid; t < P2R*28; t += 512) {
        const int r = t / 28;
        const int g = t - r*28;
        int yy = yb - 16 + r;
        yy = (yy < 0) ? 0 : (yy > SZW-1 ? SZW-1 : yy);
        __builtin_amdgcn_global_load_lds(
            (const __attribute__((address_space(1))) void*)(wp + (size_t)yy*SZW + g*8),
            (__attribute__((address_space(3))) void*)(&tile[(size_t)t*8]),
            16, 0, 0);
    }
    __syncthreads();

    // ---- zero the out-of-range boundary rows (top block: rows 0..15 of the
    //      stage = y<0; bottom block: rows 128..142 = y>223) ----
    if (blockIdx.y == 0) {
        for (int t = tid; t < 16*28; t += 512)
            *reinterpret_cast<uint4*>(&tile[(size_t)t*8]) = make_uint4(0u,0u,0u,0u);
    } else {
        for (int t = tid; t < 15*28; t += 512)
            *reinterpret_cast<uint4*>(&tile[(size_t)(128*28 + t)*8]) = make_uint4(0u,0u,0u,0u);
    }
    __syncthreads();

    // ---- compute: 448 threads = 112 col-pairs x 4 groups of 2 chunks ----
    if (tid < 448) {
        const int cp = tid % 112;          // column pair -> cols 2cp, 2cp+1
        const int gq = tid / 112;          // 0..3 -> chunks {2gq, 2gq+1}
        const int x0 = cp * 2;
        float* oc = out + (size_t)ch * PLANE + x0;

        p2_chunk(tile, ga, oc, yb, gq*2,     x0);
        p2_chunk(tile, ga, oc, yb, gq*2 + 1, x0);
    }
}

extern "C" void kernel_launch(void* const* d_in, const int* in_sizes, int n_in,
                              void* d_out, int out_size, void* d_ws, size_t ws_size,
                              hipStream_t stream)
{
    const float* x  = (const float*)d_in[0];
    float*      out = (float*)d_out;
    __half*     ws  = (__half*)d_ws;  // 768*224*224*2 = 77,070,336 B

    // Host-computed Gaussian weights (double precision then rounded to f32 —
    // matches reference _gauss float64 path).
    GaussArgs ga;
    const double c0 = 1.0 / sqrt(2.0 * 3.14159265358979323846);
    for (int k = 0; k < 32; ++k) {
        double t = -1.0 + 2.0 * (double)k / 31.0;
        ga.wx[k] = (float)(c0 * exp(-t * t / 2.0));
    }
    ga.w31 = (float)c0;
    ga.w30 = (float)(c0 * exp(-0.5));

    dim3 g1(SZW, 6, 4);               // (y, phase*freqgroup, img)
    pass1_kernel<<<g1, 512, 0, stream>>>(x, ws, ga);
    dim3 g2(768, 2);                  // (channel, y-tile)
    pass2_kernel<<<g2, 512, 0, stream>>>(ws, out, ga);
}